// Round 1
// 3049.594 us; speedup vs baseline: 1.5830x; 1.5830x over previous
//
#include <hip/hip_runtime.h>
#include <stdint.h>

// ---------------------------------------------------------------------------
// 2-layer LSTM, B=64, T=512, E=512, H=1024, then [64,1024]@V.T+bV -> [64,10].
//
// Round 7: geometry attack on the per-tick data path (all pipes idle; R4-R6
// flag-topology tweaks were null -> spine is per-tick L2 traffic + latency).
//  - batch split G=2 (rows 0-31 / 32-63): per-batch-row recurrences are
//    independent, groups never communicate. 64 col-WGs x 16 cols per layer
//    per group (256 WGs total, unchanged grid).
//  - per-tick reads halve: L0 WG reads 96KB, L1 WG 128KB (row-minimal).
//  - weights: kb<32 in LDS (128KB), kb>=32 in registers (static-indexed
//    bf16x8 rf[8][4], full unroll) -> C=16 despite 160KB LDS cap.
//  - K split 4 ways across waves; partial reduction via padded LDS tiles
//    (stride-17 rows: 2-way epilogue reads, 4-way writes, vs 8-16-way).
//  - epilogue: 512 threads x 1 cell; h stored as packed u32 in 32B
//    sector-aligned runs (16 contiguous cols/row per WG).
//  - deps shrink to 64 producers/set: single 64-lane poll load per set.
//  - ring + revolution rendezvous/acquire-fence + banked flags kept.
// ---------------------------------------------------------------------------

typedef __attribute__((ext_vector_type(8))) short bf16x8;   // 8 bf16 in 4 VGPRs
typedef __attribute__((ext_vector_type(4))) float f32x4;

__device__ __forceinline__ unsigned short f2bf(float x) {
    unsigned u = __float_as_uint(x);
    u = (u + 0x7FFFu + ((u >> 16) & 1u)) >> 16;   // RNE
    return (unsigned short)u;
}

__device__ __forceinline__ f32x4 mfma16(bf16x8 a, bf16x8 b, f32x4 c) {
    return __builtin_amdgcn_mfma_f32_16x16x32_bf16(a, b, c, 0, 0, 0);
}

// agent-scope (IC-direct) 16B load — fallback path only
__device__ __forceinline__ bf16x8 ldh(const unsigned short* p) {
    union { unsigned long long q[2]; bf16x8 v; } u;
    unsigned long long* a = (unsigned long long*)p;
    u.q[0] = __hip_atomic_load(a + 0, __ATOMIC_RELAXED, __HIP_MEMORY_SCOPE_AGENT);
    u.q[1] = __hip_atomic_load(a + 1, __ATOMIC_RELAXED, __HIP_MEMORY_SCOPE_AGENT);
    return u.v;
}

// poll 64 flags (1 wave-wide sc1 load) until all >= target
__device__ __forceinline__ void poll64(const unsigned int* base, int lane,
                                       unsigned target) {
    const unsigned int* p = base + lane;
    for (;;) {
        unsigned a = __hip_atomic_load(p, __ATOMIC_RELAXED, __HIP_MEMORY_SCOPE_AGENT);
        if (__all((int)(a >= target))) break;
        __builtin_amdgcn_s_sleep(2);
    }
}

// poll 128 flags (2 wave-wide sc1 loads) until all >= target
__device__ __forceinline__ void poll128(const unsigned int* base, int lane,
                                        unsigned target) {
    const unsigned int* p0 = base + lane;
    const unsigned int* p1 = base + 64 + lane;
    for (;;) {
        unsigned a = __hip_atomic_load(p0, __ATOMIC_RELAXED, __HIP_MEMORY_SCOPE_AGENT);
        unsigned b = __hip_atomic_load(p1, __ATOMIC_RELAXED, __HIP_MEMORY_SCOPE_AGENT);
        if (__all((int)((a >= target) && (b >= target)))) break;
        __builtin_amdgcn_s_sleep(2);
    }
}

__device__ __forceinline__ float fsigm(float x) {
    x = fminf(fmaxf(x, -60.f), 60.f);
    return __builtin_amdgcn_rcpf(1.f + __expf(-x));
}
__device__ __forceinline__ float ftanh(float x) {
    x = fminf(fmaxf(x, -15.f), 15.f);
    float e = __expf(-2.f * x);
    return (1.f - e) * __builtin_amdgcn_rcpf(1.f + e);
}

// ---------------- embedding gather + bf16 convert --------------------------
__global__ __launch_bounds__(256) void embed_kernel(
    const int* __restrict__ x, const float* __restrict__ emb,
    unsigned short* __restrict__ xs)
{
    int e = blockIdx.x * 256 + threadIdx.x;     // 0 .. 2097151
    int t  = e >> 12;
    int r  = e & 4095;
    int b  = r >> 6;
    int k8 = (r & 63) << 3;
    int tok = x[b * 512 + t];                   // x[b][t]
    const float* src = emb + (size_t)tok * 512 + k8;
    unsigned short* dst = xs + ((size_t)(t * 64 + b)) * 512 + k8;
#pragma unroll
    for (int i = 0; i < 8; ++i) dst[i] = f2bf(src[i]);
}

__global__ __launch_bounds__(256) void init_kernel(unsigned int* __restrict__ p, int n)
{
    int i = blockIdx.x * 256 + threadIdx.x;
    if (i < n) p[i] = 0u;
}

#define LDS_GWS_OFF 131072
#define GWS_TILE    272      // 16x16 f32 tile, row stride 17 (pad)
#define LDS_TOTAL   148480   // 131072 Afrag + 16*272*4 gws
#define RELIDX      2048
#define RING_MASK   127
#define SLOT_USH    65536    // 64*1024 ushorts per ring slot (131072 B)
#define NBANK       16
// flags: bar[bank*256 + layer*128 + g*64 + w], bank<16. 16 KB total.

// ---------------- persistent LSTM kernel: G2 x C16 DATAFLOW ----------------
__global__ __launch_bounds__(512) void lstm_kernel_df(
    const unsigned short* __restrict__ xs,
    unsigned short* __restrict__ h0ring,  // [128][64][1024] bf16
    unsigned short* __restrict__ h1ring,  // [128][64][1024] bf16
    float* __restrict__ h1f,              // [64][1024] fp32 (final h1)
    unsigned int* __restrict__ bar,
    const float* __restrict__ W0, const float* __restrict__ b0,
    const float* __restrict__ W1, const float* __restrict__ b1)
{
    extern __shared__ char smem[];
    bf16x8* Afrag = (bf16x8*)smem;                    // [kb<32][gt<4][64 lanes]
    float*  gws   = (float*)(smem + LDS_GWS_OFF);     // 16 tiles * 272 f32

    const int wg  = blockIdx.x;
    const int tid = threadIdx.x;
    const bool isL1 = (wg >= 128);
    const int rr  = wg & 127;
    const int g   = rr >> 6;         // batch group 0/1 (rows 32g..32g+32)
    const int w   = rr & 63;         // column block (cols 16w..16w+16)
    const int w16 = w * 16;
    const float* W = isL1 ? W1 : W0;
    const int wstride = isL1 ? 2048 : 1536;
    const float* bias = isL1 ? b1 : b0;
    const unsigned int* bk = bar + (wg & (NBANK - 1)) * 256;   // my poll bank

    // ---- LDS A-fragments: kb 0..31, 4 gate-tiles, 64 lanes (131072 B) ----
    // m-tile gt rows: m16 = c*4 + s  ->  grow = c*1024 + w16 + gt*4 + s
    for (int f = tid; f < 8192; f += 512) {
        int laneE = f & 63;
        int gt    = (f >> 6) & 3;
        int kb    = f >> 8;
        int m16   = laneE & 15;
        int q     = laneE >> 4;
        int c     = m16 >> 2;
        int s     = m16 & 3;
        int grow  = c * 1024 + w16 + gt * 4 + s;
        const float* src = W + (size_t)grow * wstride + kb * 32 + q * 8;
        bf16x8 v;
#pragma unroll
        for (int i = 0; i < 8; ++i) v[i] = (short)f2bf(src[i]);
        Afrag[f] = v;
    }

    const int lane = tid & 63;
    const int wid  = tid >> 6;         // 0..7
    const int bt   = wid & 1;          // batch sub-tile (16 rows)
    const int ksh  = wid >> 1;         // K-quarter 0..3 (kb = ksh + 4j)
    const int n16  = lane & 15;
    const int q4   = lane >> 4;
    const int row  = g * 32 + bt * 16 + n16;   // global batch row (B-frags)
    const int nkreg = isL1 ? 8 : 4;

    // ---- register A-fragments: kb = 32 + ksh + 4*jr (static-indexed) ----
    bf16x8 rf[8][4];
    {
        int m16 = lane & 15;
        int q   = lane >> 4;
        int c   = m16 >> 2;
        int s   = m16 & 3;
#pragma unroll
        for (int jr = 0; jr < 8; ++jr) {
            if (jr < nkreg) {
                int kb = 32 + ksh + 4 * jr;
#pragma unroll
                for (int gt = 0; gt < 4; ++gt) {
                    int grow = c * 1024 + w16 + gt * 4 + s;
                    const float* src = W + (size_t)grow * wstride + kb * 32 + q * 8;
                    bf16x8 v;
#pragma unroll
                    for (int i = 0; i < 8; ++i) v[i] = (short)f2bf(src[i]);
                    rf[jr][gt] = v;
                }
            }
        }
    }

    // ---- epilogue mapping: 1 cell per thread ----
    const int eb   = tid >> 4;        // local batch 0..31
    const int ecol = tid & 15;        // local column 0..15
    const int ebt  = tid >> 8;        // batch sub-tile of my cell
    const int en   = eb & 15;
    const int egt  = ecol >> 2;
    const int es   = ecol & 3;
    const int erow = g * 32 + eb;     // global batch row of my cell
    float bi[4];
#pragma unroll
    for (int c = 0; c < 4; ++c) bi[c] = bias[c * 1024 + w16 + ecol];
    float cst = 0.f;
    // gate c of my cell sits at row m = c*4+es, col en of tile (ebt, half, egt)
    const float* gs0 = gws + (size_t)((ebt * 2 + 0) * 4 + egt) * GWS_TILE + es * 17 + en;
    const float* gs1 = gws + (size_t)((ebt * 2 + 1) * 4 + egt) * GWS_TILE + es * 17 + en;
    // per-wave gws write base: tile (bt, ksh&1, gt), row m = q4*4+r2, col n16
    float* gwr = gws + (size_t)((bt * 2 + (ksh & 1)) * 4) * GWS_TILE + q4 * 68 + n16;

    __syncthreads();

    f32x4 acc[4];
#pragma unroll
    for (int i = 0; i < 4; ++i) acc[i] = (f32x4){0.f, 0.f, 0.f, 0.f};

    // pre-loop: L0's xs-part for t=0 (kb = ksh+4j < 16)
    if (!isL1) {
        const unsigned short* xsp = xs + ((size_t)row) * 512 + q4 * 8;
#pragma unroll
        for (int j = 0; j < 4; ++j) {
            int kb = ksh + 4 * j;
            bf16x8 bf = *(const bf16x8*)(xsp + kb * 32);
#pragma unroll
            for (int gt = 0; gt < 4; ++gt)
                acc[gt] = mfma16(Afrag[(kb * 4 + gt) * 64 + lane], bf, acc[gt]);
        }
    }

    for (int tick = 0; tick < 513; ++tick) {
        // ---- dependency wait (group-local 64-flag sets) ----
        if (tick > 0) {
            unsigned target = (unsigned)tick;
            if ((tick & RING_MASK) == 0) {
                // rendezvous: all 256 flags >= tick, then L1+L2 invalidate
                if (wid == 0)      poll128(bk,       lane, target);
                else if (wid == 4) poll128(bk + 128, lane, target);
                __syncthreads();
                if (wid == 0)
                    __builtin_amdgcn_fence(__ATOMIC_ACQUIRE, "agent");
                __syncthreads();
            } else {
                if (wid == 0)              poll64(bk + g * 64, lane, target);       // L0(g)
                else if (isL1 && wid == 4) poll64(bk + 128 + g * 64, lane, target); // L1(g)
                __syncthreads();
            }
        }

        int t = isL1 ? (tick - 1) : tick;
        if (t >= 0 && t < 512) {
            if (!isL1) {
                // h0(t-1): my 32 rows only, ring slot (t-1)&127
                if (t > 0) {
                    const unsigned short* hp =
                        h0ring + (size_t)((t - 1) & RING_MASK) * SLOT_USH
                               + (size_t)row * 1024 + q4 * 8;
#pragma unroll
                    for (int j = 4; j < 8; ++j) {          // kb 16..31 (LDS frags)
                        int kb = ksh + 4 * j;
                        bf16x8 bf = *(const bf16x8*)(hp + (kb - 16) * 32);
#pragma unroll
                        for (int gt = 0; gt < 4; ++gt)
                            acc[gt] = mfma16(Afrag[(kb * 4 + gt) * 64 + lane], bf, acc[gt]);
                    }
#pragma unroll
                    for (int j = 0; j < 4; ++j) {          // kb 32..47 (reg frags)
                        int kb = 32 + ksh + 4 * j;
                        bf16x8 bf = *(const bf16x8*)(hp + (kb - 16) * 32);
#pragma unroll
                        for (int gt = 0; gt < 4; ++gt)
                            acc[gt] = mfma16(rf[j][gt], bf, acc[gt]);
                    }
                }
            } else {
                // h0(t): ring slot t&127 (LDS frags, kb 0..31)
                const unsigned short* hp0 =
                    h0ring + (size_t)(t & RING_MASK) * SLOT_USH
                           + (size_t)row * 1024 + q4 * 8;
#pragma unroll
                for (int j = 0; j < 8; ++j) {
                    int kb = ksh + 4 * j;
                    bf16x8 bf = *(const bf16x8*)(hp0 + kb * 32);
#pragma unroll
                    for (int gt = 0; gt < 4; ++gt)
                        acc[gt] = mfma16(Afrag[(kb * 4 + gt) * 64 + lane], bf, acc[gt]);
                }
                // h1(t-1): ring slot (t-1)&127 (reg frags, kb 32..63)
                if (t > 0) {
                    const unsigned short* hp1 =
                        h1ring + (size_t)((t - 1) & RING_MASK) * SLOT_USH
                               + (size_t)row * 1024 + q4 * 8;
#pragma unroll
                    for (int j = 0; j < 8; ++j) {
                        int kb = ksh + 4 * j;              // col block in h1
                        bf16x8 bf = *(const bf16x8*)(hp1 + kb * 32);
#pragma unroll
                        for (int gt = 0; gt < 4; ++gt)
                            acc[gt] = mfma16(rf[j][gt], bf, acc[gt]);
                    }
                }
            }

            // ---- K-quarter reduction in LDS (padded tiles) ----
            if (ksh < 2) {
#pragma unroll
                for (int gt = 0; gt < 4; ++gt)
#pragma unroll
                    for (int r2 = 0; r2 < 4; ++r2)
                        gwr[gt * GWS_TILE + r2 * 17] = acc[gt][r2];
            }
            __syncthreads();   // (A1) quarters 0,1 visible
            if (ksh >= 2) {
#pragma unroll
                for (int gt = 0; gt < 4; ++gt)
#pragma unroll
                    for (int r2 = 0; r2 < 4; ++r2)
                        gwr[gt * GWS_TILE + r2 * 17] += acc[gt][r2];
            }
            __syncthreads();   // (A2) sums complete

            // ---- epilogue: one cell per thread ----
            float xi = gs0[0]   + gs1[0]   + bi[0];
            float xf = gs0[68]  + gs1[68]  + bi[1];
            float xg = gs0[136] + gs1[136] + bi[2];
            float xo = gs0[204] + gs1[204] + bi[3];
            float si = fsigm(xi);
            float sf = fsigm(xf);
            float tg = ftanh(xg);
            float so = fsigm(xo);
            float cn = sf * cst + si * tg;
            cst = cn;
            float h  = so * ftanh(cn);
            unsigned hb  = (unsigned)f2bf(h);
            unsigned hup = (unsigned)__shfl_down((int)hb, 1);
            if (!(tid & 1)) {
                unsigned hv = hb | (hup << 16);
                unsigned short* hw =
                    (isL1 ? h1ring : h0ring) + (size_t)(t & RING_MASK) * SLOT_USH;
                unsigned int* hp32 =
                    (unsigned int*)(hw + (size_t)erow * 1024 + w16 + ecol);
                __hip_atomic_store(hp32, hv, __ATOMIC_RELAXED, __HIP_MEMORY_SCOPE_AGENT);
            }
            if (isL1 && t == 511)
                h1f[(size_t)erow * 1024 + w16 + ecol] = h;
            __syncthreads();   // (B) per-wave vmcnt(0) drain before flag
        }

        // ---- arrive: publish tick counter to all 16 banks (1 store inst) --
        if (tick < 512) {
            if (tid < NBANK) {
                __hip_atomic_store(bar + tid * 256 + (isL1 ? 128 : 0) + g * 64 + w,
                                   (unsigned)(tick + 1),
                                   __ATOMIC_RELAXED, __HIP_MEMORY_SCOPE_AGENT);
            }
#pragma unroll
            for (int i = 0; i < 4; ++i) acc[i] = (f32x4){0.f, 0.f, 0.f, 0.f};
            int tn = tick + 1;
            if (!isL1 && tn < 512) {    // xs-part overlaps flag propagation
                const unsigned short* xsp =
                    xs + ((size_t)(tn * 64 + row)) * 512 + q4 * 8;
#pragma unroll
                for (int j = 0; j < 4; ++j) {
                    int kb = ksh + 4 * j;
                    bf16x8 bf = *(const bf16x8*)(xsp + kb * 32);
#pragma unroll
                    for (int gt = 0; gt < 4; ++gt)
                        acc[gt] = mfma16(Afrag[(kb * 4 + gt) * 64 + lane], bf, acc[gt]);
                }
            }
        }
    }
}

// ---------------- persistent LSTM kernel: round-3 FALLBACK -----------------
__global__ __launch_bounds__(512) void lstm_kernel_fb(
    const unsigned short* __restrict__ xs,
    unsigned short* __restrict__ h0buf,
    unsigned short* __restrict__ h1buf,
    float* __restrict__ h1f,
    unsigned int* __restrict__ bar,
    const float* __restrict__ W0, const float* __restrict__ b0,
    const float* __restrict__ W1, const float* __restrict__ b1)
{
    extern __shared__ char smem[];
    bf16x8* Afrag = (bf16x8*)smem;
    float*  gws   = (float*)(smem + LDS_GWS_OFF);

    const int wg  = blockIdx.x;
    const int tid = threadIdx.x;
    const bool isL1 = (wg >= 128);
    const int w   = isL1 ? wg - 128 : wg;
    const int w8  = w * 8;
    const int nk  = isL1 ? 64 : 48;
    const float* W = isL1 ? W1 : W0;
    const int wstride = isL1 ? 2048 : 1536;
    const float* bias = isL1 ? b1 : b0;

    for (int f = tid; f < nk * 128; f += 512) {
        int kblk = f >> 7;
        int r    = f & 127;
        int mt   = r >> 6;
        int lane = r & 63;
        int m16  = lane & 15;
        int q    = lane >> 4;
        int c    = m16 >> 2;
        int ul   = mt * 4 + (m16 & 3);
        int grow = c * 1024 + w8 + ul;
        const float* src = W + (size_t)grow * wstride + kblk * 32 + q * 8;
        bf16x8 v;
#pragma unroll
        for (int i = 0; i < 8; ++i) v[i] = (short)f2bf(src[i]);
        Afrag[f] = v;
    }

    const int lane = tid & 63;
    const int wid  = tid >> 6;
    const int wv   = wid & 3;
    const int kh   = tid >> 8;
    const int n16  = lane & 15;
    const int q4   = lane >> 4;
    const int brow = wv * 16 + n16;

    float bi[2][4];
#pragma unroll
    for (int cell = 0; cell < 2; ++cell) {
        int j = w8 + q4 * 2 + cell;
#pragma unroll
        for (int c = 0; c < 4; ++c) bi[cell][c] = bias[c * 1024 + j];
    }
    float cst0 = 0.f, cst1 = 0.f;

    __syncthreads();

    f32x4 acc0 = (f32x4){0.f, 0.f, 0.f, 0.f};
    f32x4 acc1 = (f32x4){0.f, 0.f, 0.f, 0.f};

    if (!isL1) {
        const unsigned short* xsp = xs + ((size_t)brow) * 512 + q4 * 8;
        int k0 = kh ? 8 : 0;
#pragma unroll
        for (int kb2 = 0; kb2 < 8; ++kb2) {
            int kb = k0 + kb2;
            bf16x8 bf = *(const bf16x8*)(xsp + kb * 32);
            acc0 = mfma16(Afrag[(kb * 2 + 0) * 64 + lane], bf, acc0);
            acc1 = mfma16(Afrag[(kb * 2 + 1) * 64 + lane], bf, acc1);
        }
    }

    for (int tick = 0; tick < 513; ++tick) {
        if (tick > 0) {
            unsigned target = (unsigned)tick;
            if (wg == 0) {
                if (tid < 256) {
                    while (__hip_atomic_load(&bar[tid * 8], __ATOMIC_RELAXED,
                                             __HIP_MEMORY_SCOPE_AGENT) < target)
                        __builtin_amdgcn_s_sleep(1);
                }
                __syncthreads();
                if (tid < 8)
                    __hip_atomic_store(&bar[RELIDX + tid * 32], target,
                                       __ATOMIC_RELAXED, __HIP_MEMORY_SCOPE_AGENT);
            } else {
                if (tid == 0) {
                    while (__hip_atomic_load(&bar[RELIDX + (wg & 7) * 32],
                                             __ATOMIC_RELAXED,
                                             __HIP_MEMORY_SCOPE_AGENT) < target)
                        __builtin_amdgcn_s_sleep(1);
                }
                __syncthreads();
            }
            asm volatile("" ::: "memory");
        }

        int t = isL1 ? (tick - 1) : tick;
        if (t >= 0 && t < 512) {
            const int p = t & 1;

            if (!isL1) {
                const unsigned short* hp =
                    h0buf + (size_t)(p ^ 1) * 65536 + (size_t)brow * 1024 + q4 * 8;
                int k0 = kh ? 32 : 16;
#pragma unroll 8
                for (int kb2 = 0; kb2 < 16; ++kb2) {
                    int kb = k0 + kb2;
                    bf16x8 bf = ldh(hp + (kb - 16) * 32);
                    acc0 = mfma16(Afrag[(kb * 2 + 0) * 64 + lane], bf, acc0);
                    acc1 = mfma16(Afrag[(kb * 2 + 1) * 64 + lane], bf, acc1);
                }
            } else if (kh == 0) {
                const unsigned short* hp0 =
                    h0buf + (size_t)p * 65536 + (size_t)brow * 1024 + q4 * 8;
#pragma unroll 8
                for (int kb = 0; kb < 32; ++kb) {
                    bf16x8 bf = ldh(hp0 + kb * 32);
                    acc0 = mfma16(Afrag[(kb * 2 + 0) * 64 + lane], bf, acc0);
                    acc1 = mfma16(Afrag[(kb * 2 + 1) * 64 + lane], bf, acc1);
                }
            } else {
                const unsigned short* hp1 =
                    h1buf + (size_t)(p ^ 1) * 65536 + (size_t)brow * 1024 + q4 * 8;
#pragma unroll 8
                for (int kb = 32; kb < 64; ++kb) {
                    bf16x8 bf = ldh(hp1 + (kb - 32) * 32);
                    acc0 = mfma16(Afrag[(kb * 2 + 0) * 64 + lane], bf, acc0);
                    acc1 = mfma16(Afrag[(kb * 2 + 1) * 64 + lane], bf, acc1);
                }
            }

            float* gq = gws + wid * 512;
#pragma unroll
            for (int r = 0; r < 4; ++r) {
                gq[      q4 * 64 + r * 16 + n16] = acc0[r];
                gq[256 + q4 * 64 + r * 16 + n16] = acc1[r];
            }
            __syncthreads();

            if (kh == 0) {
                unsigned short* hw = (isL1 ? h1buf : h0buf) + (size_t)p * 65536;
                unsigned short hbits[2];
                float hflt[2];
#pragma unroll
                for (int cell = 0; cell < 2; ++cell) {
                    int ul = q4 * 2 + cell;
                    int mt = ul >> 2;
                    int r  = ul & 3;
                    const float* g0 = gws + wv * 512 + mt * 256;
                    const float* g1 = gws + (wv + 4) * 512 + mt * 256;
                    float xi = g0[0 * 64 + r * 16 + n16] + g1[0 * 64 + r * 16 + n16] + bi[cell][0];
                    float xf = g0[1 * 64 + r * 16 + n16] + g1[1 * 64 + r * 16 + n16] + bi[cell][1];
                    float xg = g0[2 * 64 + r * 16 + n16] + g1[2 * 64 + r * 16 + n16] + bi[cell][2];
                    float xo = g0[3 * 64 + r * 16 + n16] + g1[3 * 64 + r * 16 + n16] + bi[cell][3];
                    float si = fsigm(xi);
                    float sf = fsigm(xf);
                    float tg = ftanh(xg);
                    float so = fsigm(xo);
                    float cprev = cell ? cst1 : cst0;
                    float cn = sf * cprev + si * tg;
                    if (cell) cst1 = cn; else cst0 = cn;
                    float h = so * ftanh(cn);
                    hflt[cell]  = h;
                    hbits[cell] = f2bf(h);
                }
                unsigned int hv = (unsigned)hbits[0] | ((unsigned)hbits[1] << 16);
                unsigned int* hp32 =
                    (unsigned int*)(hw + (size_t)brow * 1024 + w8 + q4 * 2);
                __hip_atomic_store(hp32, hv, __ATOMIC_RELAXED, __HIP_MEMORY_SCOPE_AGENT);
                if (isL1 && t == 511) {
                    h1f[(size_t)brow * 1024 + w8 + q4 * 2 + 0] = hflt[0];
                    h1f[(size_t)brow * 1024 + w8 + q4 * 2 + 1] = hflt[1];
                }
            }
            __syncthreads();
        }

        if (tick < 512) {
            if (tid == 0) {
                asm volatile("s_waitcnt vmcnt(0)" ::: "memory");
                __hip_atomic_store(&bar[wg * 8], (unsigned)(tick + 1),
                                   __ATOMIC_RELAXED, __HIP_MEMORY_SCOPE_AGENT);
            }
            acc0 = (f32x4){0.f, 0.f, 0.f, 0.f};
            acc1 = (f32x4){0.f, 0.f, 0.f, 0.f};
            int tn = tick + 1;
            if (!isL1 && tn < 512) {
                const unsigned short* xsp =
                    xs + ((size_t)(tn * 64 + brow)) * 512 + q4 * 8;
                int k0 = kh ? 8 : 0;
#pragma unroll
                for (int kb2 = 0; kb2 < 8; ++kb2) {
                    int kb = k0 + kb2;
                    bf16x8 bf = *(const bf16x8*)(xsp + kb * 32);
                    acc0 = mfma16(Afrag[(kb * 2 + 0) * 64 + lane], bf, acc0);
                    acc1 = mfma16(Afrag[(kb * 2 + 1) * 64 + lane], bf, acc1);
                }
            }
        }
    }
}

// ---------------- classifier: out = h1f @ V.T + bV -------------------------
__global__ __launch_bounds__(64) void cls_kernel(
    const float* __restrict__ h1f, const float* __restrict__ V,
    const float* __restrict__ bV, float* __restrict__ out)
{
    int b = blockIdx.x;
    int lane = threadIdx.x;
    float p[10];
#pragma unroll
    for (int c = 0; c < 10; ++c) p[c] = 0.f;
    for (int k = lane; k < 1024; k += 64) {
        float h = h1f[(size_t)b * 1024 + k];
#pragma unroll
        for (int c = 0; c < 10; ++c) p[c] += h * V[(size_t)c * 1024 + k];
    }
#pragma unroll
    for (int c = 0; c < 10; ++c) {
        float v = p[c];
#pragma unroll
        for (int off = 32; off > 0; off >>= 1) v += __shfl_down(v, off);
        if (lane == 0) out[b * 10 + c] = v + bV[c];
    }
}

// ---------------- launch ---------------------------------------------------
// RING ws layout (bytes), total 67,387,392:
//   [0, 33554432)            xs  bf16 [512][64][512]
//   +33554432  h0ring bf16 [128][64][1024]   (16777216)
//   +50331648  h1ring bf16 [128][64][1024]   (16777216)
//   +67108864  h1f    fp32 [64][1024]        (262144)
//   +67371008  flags  [16 banks][256] u32    (16384)
// FALLBACK layout: as round 3 (34.3 MB).
extern "C" void kernel_launch(void* const* d_in, const int* in_sizes, int n_in,
                              void* d_out, int out_size, void* d_ws, size_t ws_size,
                              hipStream_t stream)
{
    const int*   x   = (const int*)d_in[0];
    const float* emb = (const float*)d_in[1];
    const float* W0  = (const float*)d_in[2];
    const float* b0  = (const float*)d_in[3];
    const float* W1  = (const float*)d_in[4];
    const float* b1  = (const float*)d_in[5];
    const float* V   = (const float*)d_in[6];
    const float* bV  = (const float*)d_in[7];
    float* out = (float*)d_out;

    char* ws = (char*)d_ws;
    unsigned short* xs = (unsigned short*)ws;

    if (ws_size >= 67387392ULL) {
        unsigned short* h0r = (unsigned short*)(ws + 33554432);
        unsigned short* h1r = (unsigned short*)(ws + 50331648);
        float*          h1f = (float*)(ws + 67108864);
        unsigned int*   bar = (unsigned int*)(ws + 67371008);

        hipLaunchKernelGGL(init_kernel, dim3(16), dim3(256), 0, stream,
                           bar, 4096);
        hipLaunchKernelGGL(embed_kernel, dim3(8192), dim3(256), 0, stream, x, emb, xs);
        hipLaunchKernelGGL(lstm_kernel_df, dim3(256), dim3(512), LDS_TOTAL, stream,
                           xs, h0r, h1r, h1f, bar, W0, b0, W1, b1);
        hipLaunchKernelGGL(cls_kernel, dim3(64), dim3(64), 0, stream, h1f, V, bV, out);
    } else {
        char* dyn = ws + 33554432;
        unsigned short* h0  = (unsigned short*)(dyn);
        unsigned short* h1  = (unsigned short*)(dyn + 262144);
        float*          h1f = (float*)(dyn + 524288);
        unsigned int*   bar = (unsigned int*)(dyn + 786432);

        hipLaunchKernelGGL(init_kernel, dim3(780), dim3(256), 0, stream,
                           (unsigned int*)dyn, 199680);
        hipLaunchKernelGGL(embed_kernel, dim3(8192), dim3(256), 0, stream, x, emb, xs);
        hipLaunchKernelGGL(lstm_kernel_fb, dim3(256), dim3(512), LDS_TOTAL, stream,
                           xs, h0, h1, h1f, bar, W0, b0, W1, b1);
        hipLaunchKernelGGL(cls_kernel, dim3(64), dim3(64), 0, stream, h1f, V, bV, out);
    }
}